// Round 10
// baseline (172.932 us; speedup 1.0000x reference)
//
#include <hip/hip_runtime.h>

typedef __bf16 bf16_t;
typedef __bf16 bf16x8 __attribute__((ext_vector_type(8)));
typedef __bf16 bf16x4 __attribute__((ext_vector_type(4)));
typedef float f32x4 __attribute__((ext_vector_type(4)));
typedef short short4v __attribute__((ext_vector_type(4)));

#if __has_builtin(__builtin_amdgcn_exp2f)
#define EXP2F __builtin_amdgcn_exp2f
#else
#define EXP2F exp2f
#endif

// ---------------- constants (problem shape is fixed) ----------------
#define BATCH 2
#define SEQ   2048
#define DIM   1024
#define NQH   16
#define NKVH  4
#define HD    64
#define ROWS  (BATCH*SEQ)      // 4096
#define QKVN  1536             // 1024 q + 256 k + 256 v
#define QSCALE 0.1803368801111f   // 0.125 * log2(e), folded into Q at projection

static __device__ __forceinline__ short4v as_s4(bf16x4 v) {
    union { bf16x4 b; short4v s; } u; u.b = v; return u.s;
}

// async global->LDS DMA, 16B per lane, LDS dest = wave-uniform base + lane*16
static __device__ __forceinline__ void gld16(const bf16_t* g, bf16_t* l) {
    __builtin_amdgcn_global_load_lds((const __attribute__((address_space(1))) void*)g,
                                     (__attribute__((address_space(3))) void*)l,
                                     16, 0, 0);
}

// ============ all 4 weight transposes in ONE dispatch ============
__global__ __launch_bounds__(256) void transpose_w_all(const float* __restrict__ wq,
                                                       const float* __restrict__ wk,
                                                       const float* __restrict__ wv,
                                                       const float* __restrict__ wo,
                                                       bf16_t* __restrict__ WqkvT,
                                                       bf16_t* __restrict__ WoT) {
    int bid = blockIdx.x;          // 0..639
    const float* src; bf16_t* dst; int N, nt, kt2;
    if (bid < 256)      { src = wq; dst = WqkvT;                      N = 1024; int i = bid;       nt = i & 15; kt2 = i >> 4; }
    else if (bid < 320) { src = wk; dst = WqkvT + (size_t)1024*1024;  N = 256;  int i = bid - 256; nt = i & 3;  kt2 = i >> 2; }
    else if (bid < 384) { src = wv; dst = WqkvT + (size_t)1280*1024;  N = 256;  int i = bid - 320; nt = i & 3;  kt2 = i >> 2; }
    else                { src = wo; dst = WoT;                        N = 1024; int i = bid - 384; nt = i & 15; kt2 = i >> 4; }

    __shared__ float tile[64][65];
    int t = threadIdx.x;
    {
        int r = t >> 2, cb = (t & 3) * 16;
        const float* s = src + (size_t)(kt2 * 64 + r) * N + nt * 64 + cb;
#pragma unroll
        for (int j = 0; j < 16; j += 4) {
            float4 v = *(const float4*)(s + j);
            tile[r][cb + j + 0] = v.x; tile[r][cb + j + 1] = v.y;
            tile[r][cb + j + 2] = v.z; tile[r][cb + j + 3] = v.w;
        }
    }
    __syncthreads();
    {
        int n = t >> 2, kb = (t & 3) * 16;
        union { bf16_t h[16]; uint4 u[2]; } pk;
#pragma unroll
        for (int j = 0; j < 16; ++j) pk.h[j] = (bf16_t)tile[kb + j][n];
        bf16_t* d = dst + (size_t)(nt * 64 + n) * 1024 + kt2 * 64 + kb;
        ((uint4*)d)[0] = pk.u[0];
        ((uint4*)d)[1] = pk.u[1];
    }
}

// ======================= GEMM1: f32 x @ Wqkv^T, BM=64 BN=128 BK=64, fused cast + RoPE =======================
// A is consumed directly as FP32 (cast_x kernel deleted): per lane, 4x float4
// load -> cvt bf16 -> 2x ds_write_b128 into the SAME LDS slots the old gld16
// path produced (lane L's 16B slot = row L>>3, chunk L&7; source chunk
// pre-swizzled (L&7)^(L>>3), rule #21). B keeps the global_load_lds DMA path.
// x re-reads across the 12 bn-blocks of one bm-panel are L2-hits (consecutive
// swizzled ids share bm within an XCD). Grid 768 = 3 blocks/CU.
__global__ __launch_bounds__(256, 3) void gemm_qkv_kernel(const float* __restrict__ X,
                                                          const bf16_t* __restrict__ Bt,
                                                          const float* __restrict__ fcos,
                                                          const float* __restrict__ fsin,
                                                          bf16_t* __restrict__ Qb,
                                                          bf16_t* __restrict__ Kb,
                                                          bf16_t* __restrict__ Vt) {
    const int K = 1024;
    __shared__ __align__(16) bf16_t As[64 * 64];
    __shared__ __align__(16) bf16_t Bs[128 * 64];
    int t = threadIdx.x;
    int w = t >> 6, L = t & 63, quad = L >> 4, l15 = L & 15;
    int wr = (w >> 1) * 32, wc = (w & 1) * 64;

    int xid = blockIdx.x;                  // 0..767
    int sw = (xid & 7) * 96 + (xid >> 3);  // bijective XCD swizzle (768 % 8 == 0)
    int bnb = sw % 12;
    int bm = (sw / 12) * 64, bn = bnb * 128;

    int srow = L >> 3;                     // 0..7
    int schunk = (L & 7) ^ srow;           // pre-swizzled global source chunk
    const float*  Ax = X  + (size_t)(bm + w * 16 + srow) * K + schunk * 8;
    const bf16_t* Bg = Bt + (size_t)(bn + w * 32 + srow) * K + schunk * 8;
    bf16_t* Ad0 = As + w * 1024 + L * 8;   // lane's 16B slot (row srow, chunk L&7)
    bf16_t* Bl  = Bs + w * 2048;

    int rs0 = quad ^ (l15 & 7);            // read slot, kk=0
    int rs1 = (4 + quad) ^ (l15 & 7);      // read slot, kk=1

    f32x4 acc[2][4] = {};

    for (int k0 = 0; k0 < K; k0 += 64) {
        __syncthreads();
        // A: f32 loads (issue first so latency overlaps B's DMA issue)
        float4 a0 = *(const float4*)(Ax + k0);
        float4 a1 = *(const float4*)(Ax + k0 + 4);
        float4 a2 = *(const float4*)(Ax + (size_t)8 * K + k0);
        float4 a3 = *(const float4*)(Ax + (size_t)8 * K + k0 + 4);
        // B: async DMA
#pragma unroll
        for (int c = 0; c < 4; ++c)
            gld16(Bg + (size_t)(c * 8) * K + k0, Bl + c * 512);
        // A: convert + LDS write (same slots as the old gld16 layout)
        bf16x8 v0, v1;
        v0[0] = (bf16_t)a0.x; v0[1] = (bf16_t)a0.y; v0[2] = (bf16_t)a0.z; v0[3] = (bf16_t)a0.w;
        v0[4] = (bf16_t)a1.x; v0[5] = (bf16_t)a1.y; v0[6] = (bf16_t)a1.z; v0[7] = (bf16_t)a1.w;
        v1[0] = (bf16_t)a2.x; v1[1] = (bf16_t)a2.y; v1[2] = (bf16_t)a2.z; v1[3] = (bf16_t)a2.w;
        v1[4] = (bf16_t)a3.x; v1[5] = (bf16_t)a3.y; v1[6] = (bf16_t)a3.z; v1[7] = (bf16_t)a3.w;
        *(bf16x8*)Ad0 = v0;
        *(bf16x8*)(Ad0 + 512) = v1;
        __syncthreads();                   // drains ds_write (lgkm) + DMA (vmcnt)

#pragma unroll
        for (int kk = 0; kk < 2; ++kk) {
            int rsl = kk ? rs1 : rs0;
            bf16x8 a[2], b[4];
#pragma unroll
            for (int i = 0; i < 2; ++i)
                a[i] = ((const bf16x8*)As)[(wr + 16 * i + l15) * 8 + rsl];
#pragma unroll
            for (int j = 0; j < 4; ++j)
                b[j] = ((const bf16x8*)Bs)[(wc + 16 * j + l15) * 8 + rsl];
#pragma unroll
            for (int i = 0; i < 2; ++i)
#pragma unroll
                for (int j = 0; j < 4; ++j)
                    acc[i][j] = __builtin_amdgcn_mfma_f32_16x16x32_bf16(a[i], b[j], acc[i][j], 0, 0, 0);
        }
    }

    // ---- fused epilogue ----
    int region = (bnb >= 10) ? 2 : (bnb >= 8) ? 1 : 0;
#pragma unroll
    for (int i = 0; i < 2; ++i) {
        int row0 = bm + wr + 16 * i + quad * 4;
        int b = row0 >> 11, s0 = row0 & 2047;
#pragma unroll
        for (int j = 0; j < 4; ++j) {
            int col = bn + wc + 16 * j + l15;
            if (region == 2) {                      // V: write Vt[b][kv][d][s], 4 consecutive s
                int kvh = (col >> 6) - 20, d = col & 63;
                bf16x4 o;
#pragma unroll
                for (int r = 0; r < 4; ++r) o[r] = (bf16_t)acc[i][j][r];
                *(bf16x4*)(Vt + ((size_t)((b * NKVH + kvh) * HD + d)) * SEQ + s0) = o;
            } else {                                // Q or K: RoPE
                int d = col & 63, fi = d >> 1;
                int odd = col & 1;
#pragma unroll
                for (int r = 0; r < 4; ++r) {
                    int s = s0 + r;
                    float v = acc[i][j][r];
                    float p = __shfl_xor(v, 1);
                    float c = fcos[s * 32 + fi], sn = fsin[s * 32 + fi];
                    float o = odd ? (p * sn + v * c) : (v * c - p * sn);
                    if (region == 0) {
                        int h = col >> 6;
                        Qb[((size_t)((b * NQH + h) * SEQ + s)) * HD + d] = (bf16_t)(o * QSCALE);
                    } else {
                        int kvh = (col >> 6) - 16;
                        Kb[((size_t)((b * NKVH + kvh) * SEQ + s)) * HD + d] = (bf16_t)o;
                    }
                }
            }
        }
    }
}

// ======================= GEMM2: attn @ Wo^T, BM=64 BN=128 BK=64 (R4 proven) =======================
__global__ __launch_bounds__(256, 2) void gemm_bt_kernel(const bf16_t* __restrict__ A,
                                                         const bf16_t* __restrict__ Bt,
                                                         float* __restrict__ C) {
    const int K = 1024, N = 1024;
    __shared__ __align__(16) bf16_t As[64 * 64];
    __shared__ __align__(16) bf16_t Bs[128 * 64];
    int t = threadIdx.x;
    int w = t >> 6, L = t & 63, quad = L >> 4, l15 = L & 15;
    int wr = (w >> 1) * 32, wc = (w & 1) * 64;

    int xid = blockIdx.x;                  // 0..511
    int sw = (xid & 7) * 64 + (xid >> 3);  // bijective XCD swizzle (512 % 8 == 0)
    int bm = (sw >> 3) * 64, bn = (sw & 7) * 128;

    int srow = L >> 3;
    int schunk = (L & 7) ^ srow;
    const bf16_t* Ag = A  + (size_t)(bm + w * 16 + srow) * K + schunk * 8;
    const bf16_t* Bg = Bt + (size_t)(bn + w * 32 + srow) * K + schunk * 8;
    bf16_t* Al = As + w * 1024;
    bf16_t* Bl = Bs + w * 2048;

    int rs0 = quad ^ (l15 & 7);
    int rs1 = (4 + quad) ^ (l15 & 7);

    f32x4 acc[2][4] = {};

    for (int k0 = 0; k0 < K; k0 += 64) {
        __syncthreads();
        gld16(Ag + k0,                 Al);
        gld16(Ag + (size_t)8 * K + k0, Al + 512);
#pragma unroll
        for (int c = 0; c < 4; ++c)
            gld16(Bg + (size_t)(c * 8) * K + k0, Bl + c * 512);
        __syncthreads();

#pragma unroll
        for (int kk = 0; kk < 2; ++kk) {
            int rsl = kk ? rs1 : rs0;
            bf16x8 a[2], b[4];
#pragma unroll
            for (int i = 0; i < 2; ++i)
                a[i] = ((const bf16x8*)As)[(wr + 16 * i + l15) * 8 + rsl];
#pragma unroll
            for (int j = 0; j < 4; ++j)
                b[j] = ((const bf16x8*)Bs)[(wc + 16 * j + l15) * 8 + rsl];
#pragma unroll
            for (int i = 0; i < 2; ++i)
#pragma unroll
                for (int j = 0; j < 4; ++j)
                    acc[i][j] = __builtin_amdgcn_mfma_f32_16x16x32_bf16(a[i], b[j], acc[i][j], 0, 0, 0);
        }
    }

#pragma unroll
    for (int i = 0; i < 2; ++i) {
        int row = bm + wr + 16 * i + quad * 4;
#pragma unroll
        for (int j = 0; j < 4; ++j) {
            int col = bn + wc + 16 * j + l15;
            float* cp = C + (size_t)row * N + col;
#pragma unroll
            for (int r = 0; r < 4; ++r)
                cp[(size_t)r * N] = acc[i][j][r];
        }
    }
}

// ======================= flash attention, causal, GQA 4:1 — KEY-SPLIT WAVES (R9, kept) =======================
__global__ __launch_bounds__(256, 2) void attn_kernel(const bf16_t* __restrict__ Qb,
                                                      const bf16_t* __restrict__ Kb,
                                                      const bf16_t* __restrict__ Vt,
                                                      bf16_t* __restrict__ Ob) {
    int id = blockIdx.x;                       // 0..511
    int sw = (id & 7) * 64 + (id >> 3);        // bijective XCD swizzle (512 % 8 == 0)
    int b  = sw >> 8;
    int kv = (sw >> 6) & 3;
    int h  = kv * 4 + ((sw >> 4) & 3);
    int p  = sw & 15;                          // q-tiles {p, 31-p}

    int t = threadIdx.x, w = t >> 6, lane = t & 63, quad = lane >> 4, l15 = lane & 15;

    // 69632 B aliased: staging {Ks[2] 2x8192 elems, Vs[2] 2x8192 elems} / reduction f32[4][64][68]
    __shared__ __align__(16) char smem[69632];
    __shared__ float rsw[4][64];
    bf16_t* KsBuf = (bf16_t*)smem;             // Ks[buf] at buf*8192 elems
    bf16_t* VsBuf = (bf16_t*)smem + 16384;     // Vs[buf] at buf*8192 elems
    float*  red   = (float*)smem;              // [w][q 64][d 68] idx = w*4352 + q*68 + d

    const bf16_t* Qbase = Qb + ((size_t)(b * NQH + h)) * SEQ * HD;
    const bf16_t* Kbase = Kb + ((size_t)(b * NKVH + kv)) * SEQ * HD;
    const bf16_t* Vbase = Vt + ((size_t)(b * NKVH + kv)) * HD * SEQ;

    // staging: K chunk o=t+256j: row=o>>3,c=o&7; V: row=o>>4,c=o&15; src chunk c^(row&7)
    const bf16_t* kS0 = Kbase + (size_t)(t >> 3) * HD + (size_t)(((t & 7) ^ ((t >> 3) & 7)) * 8);
    const bf16_t* vS0 = Vbase + (size_t)(t >> 4) * SEQ + (size_t)(((t & 15) ^ ((t >> 4) & 7)) * 8);
    int ldso = w * 512;

#pragma unroll 1
    for (int ph = 0; ph < 2; ++ph) {
        int qt = ph ? (31 - p) : p;
        int Q0 = qt * 64;
        int ktmax = qt >> 1;                   // inclusive, 128-key tiles

        bf16x8 aq[4][2];                       // ALL 64 q-rows in registers
#pragma unroll
        for (int j = 0; j < 4; ++j)
#pragma unroll
            for (int ks = 0; ks < 2; ++ks)
                aq[j][ks] = *(const bf16x8*)(Qbase + (size_t)(Q0 + 16 * j + l15) * HD + ks * 32 + quad * 8);

        f32x4 acc[4][4] = {};                  // partial O over this wave's keys
        float rs[4] = {};

        __syncthreads();                       // prev-phase reduction reads done
#pragma unroll
        for (int j4 = 0; j4 < 4; ++j4) {
            gld16(kS0 + (size_t)j4 * 32 * HD,  KsBuf + ldso + j4 * 2048);
            gld16(vS0 + (size_t)j4 * 16 * SEQ, VsBuf + ldso + j4 * 2048);
        }

        int cur = 0;
        for (int kt = 0; kt <= ktmax; ++kt) {
            __syncthreads();                   // drains own gld16; buf[cur] ready
            if (kt < ktmax) {
                const bf16_t* kp = kS0 + (size_t)(kt + 1) * 128 * HD;
                const bf16_t* vp = vS0 + (size_t)(kt + 1) * 128;
                bf16_t* kd = KsBuf + (cur ^ 1) * 8192 + ldso;
                bf16_t* vd = VsBuf + (cur ^ 1) * 8192 + ldso;
#pragma unroll
                for (int j4 = 0; j4 < 4; ++j4) {
                    gld16(kp + (size_t)j4 * 32 * HD,  kd + j4 * 2048);
                    gld16(vp + (size_t)j4 * 16 * SEQ, vd + j4 * 2048);
                }
            }
            const bf16_t* KsC = KsBuf + cur * 8192;
            const bf16_t* VsC = VsBuf + cur * 8192;

            // even-qt diagonal: waves 2,3 fully masked -> uniform skip
            if (!(kt == ktmax && !(qt & 1) && w >= 2)) {
                short4v bp[2][4];
                if (kt == ktmax) {             // diagonal tile: mask
#pragma unroll
                    for (int g2 = 0; g2 < 2; ++g2) {
                        int g = 2 * w + g2;
                        int keyl = 16 * g + l15;
                        bf16x8 ak0 = ((const bf16x8*)KsC)[keyl * 8 + (quad ^ (keyl & 7))];
                        bf16x8 ak1 = ((const bf16x8*)KsC)[keyl * 8 + ((4 + quad) ^ (keyl & 7))];
                        int kb = kt * 128 + 16 * g + quad * 4;
#pragma unroll
                        for (int j = 0; j < 4; ++j) {
                            f32x4 z = {0.f, 0.f, 0.f, 0.f};
                            z = __builtin_amdgcn_mfma_f32_16x16x32_bf16(ak0, aq[j][0], z, 0, 0, 0);
                            z = __builtin_amdgcn_mfma_f32_16x16x32_bf16(ak1, aq[j][1], z, 0, 0, 0);
                            int qrow = Q0 + 16 * j + l15;
                            bf16x4 pb;
#pragma unroll
                            for (int r = 0; r < 4; ++r) {
                                float pv = (kb + r <= qrow) ? EXP2F(z[r]) : 0.f;
                                rs[j] += pv; pb[r] = (bf16_t)pv;
                            }
                            bp[g2][j] = as_s4(pb);
                        }
                    }
                } else {                       // interior tile: no mask
#pragma unroll
                    for (int g2 = 0; g2 < 2; ++g2) {
                        int g = 2 * w + g2;
                        int keyl = 16 * g + l15;
                        bf16x8 ak0 = ((const bf16x8*)KsC)[keyl * 8 + (quad ^ (keyl & 7))];
                        bf16x8 ak1 = ((const bf16x8*)KsC)[keyl * 8 + ((4 + quad) ^ (keyl & 7))];
#pragma unroll
                        for (int j = 0; j < 4; ++j) {
                            f32x4 z = {0.f, 0.f, 0.f, 0.f};
                            z = __builtin_amdgcn_mfma_f32_16x16x32_bf16(ak0, aq[j][0], z, 0, 0, 0);
                            z = __builtin_amdgcn_mfma_f32_16x16x32_bf16(ak1, aq[j][1], z, 0, 0, 0);
                            bf16x4 pb;
#pragma unroll
                            for (int r = 0; r < 4; ++r) {
                                float pv = EXP2F(z[r]);
                                rs[j] += pv; pb[r] = (bf16_t)pv;
                            }
                            bp[g2][j] = as_s4(pb);
                        }
                    }
                }

                // ---- O^T partial += V^T(this wave's keys) · P^T ----
                __builtin_amdgcn_s_setprio(1);
#pragma unroll
                for (int dt = 0; dt < 4; ++dt) {
                    int d = 16 * dt + l15;
#pragma unroll
                    for (int g2 = 0; g2 < 2; ++g2) {
                        int g = 2 * w + g2;
                        int pos = (2 * g + (quad >> 1)) ^ (d & 7);
                        bf16x4 av = *(const bf16x4*)(VsC + d * 128 + pos * 8 + (quad & 1) * 4);
#pragma unroll
                        for (int j = 0; j < 4; ++j)
                            acc[dt][j] = __builtin_amdgcn_mfma_f32_16x16x16bf16_1k(as_s4(av), bp[g2][j], acc[dt][j], 0, 0, 0);
                    }
                }
                __builtin_amdgcn_s_setprio(0);
            }
            cur ^= 1;
        }

        // ---- cross-wave reduction ----
        __syncthreads();                       // all K/V LDS reads done; DMA drained
        {
            float* rw = red + w * 4352;
#pragma unroll
            for (int dt = 0; dt < 4; ++dt)
#pragma unroll
                for (int j = 0; j < 4; ++j)
                    *(f32x4*)(rw + (16 * j + l15) * 68 + 16 * dt + quad * 4) = acc[dt][j];
        }
#pragma unroll
        for (int j = 0; j < 4; ++j) {
            float v = rs[j];
            v += __shfl_xor(v, 16);
            v += __shfl_xor(v, 32);
            if (quad == 0) rsw[w][16 * j + l15] = v;
        }
        __syncthreads();                       // partials + rowsums visible

        // wave w writes d-range [16w,16w+16) for all 64 q (lane = q)
        {
            int qg = Q0 + lane;
            float rtot = rsw[0][lane] + rsw[1][lane] + rsw[2][lane] + rsw[3][lane];
            float rinv = 1.0f / rtot;
            union { bf16_t hh[16]; uint4 u[2]; } pk;
#pragma unroll
            for (int dq = 0; dq < 4; ++dq) {
                f32x4 s = *(const f32x4*)(red + lane * 68 + 16 * w + 4 * dq);
#pragma unroll
                for (int w2 = 1; w2 < 4; ++w2) {
                    f32x4 tp = *(const f32x4*)(red + w2 * 4352 + lane * 68 + 16 * w + 4 * dq);
                    s[0] += tp[0]; s[1] += tp[1]; s[2] += tp[2]; s[3] += tp[3];
                }
#pragma unroll
                for (int r = 0; r < 4; ++r) pk.hh[4 * dq + r] = (bf16_t)(s[r] * rinv);
            }
            bf16_t* ob = Ob + (size_t)(b * SEQ + qg) * DIM + h * HD + 16 * w;
            ((uint4*)ob)[0] = pk.u[0];
            ((uint4*)ob)[1] = pk.u[1];
        }
    }
}

// ======================= launcher =======================
extern "C" void kernel_launch(void* const* d_in, const int* in_sizes, int n_in,
                              void* d_out, int out_size, void* d_ws, size_t ws_size,
                              hipStream_t stream) {
    const float* x    = (const float*)d_in[0];
    const float* fcos = (const float*)d_in[2];
    const float* fsin = (const float*)d_in[3];
    const float* wq   = (const float*)d_in[5];
    const float* wk   = (const float*)d_in[6];
    const float* wv   = (const float*)d_in[7];
    const float* wo   = (const float*)d_in[8];
    float* out = (float*)d_out;

    char* ws = (char*)d_ws;
    bf16_t* Attnb = (bf16_t*)(ws + 0);            //  8 MB  [4096][1024]
    bf16_t* WqkvT = (bf16_t*)(ws + 8388608);      //  3 MB  [1536][1024]
    bf16_t* WoT   = (bf16_t*)(ws + 11534336);     //  2 MB  [1024][1024]
    bf16_t* Qb    = (bf16_t*)(ws + 13631488);     //  8 MB  [B][16][S][64]
    bf16_t* Kb    = (bf16_t*)(ws + 22020096);     //  2 MB  [B][4][S][64]
    bf16_t* Vt    = (bf16_t*)(ws + 24117248);     //  2 MB  [B][4][64][S]
    // total 26,214,400 B

    transpose_w_all<<<640, 256, 0, stream>>>(wq, wk, wv, wo, WqkvT, WoT);

    gemm_qkv_kernel<<<(QKVN / 128) * (ROWS / 64), 256, 0, stream>>>(x, WqkvT, fcos, fsin, Qb, Kb, Vt);

    attn_kernel<<<512, 256, 0, stream>>>(Qb, Kb, Vt, Attnb);

    gemm_bt_kernel<<<(DIM / 128) * (ROWS / 64), 256, 0, stream>>>(Attnb, WoT, out);
}

// Round 11
// 164.251 us; speedup vs baseline: 1.0529x; 1.0529x over previous
//
#include <hip/hip_runtime.h>

typedef __bf16 bf16_t;
typedef __bf16 bf16x8 __attribute__((ext_vector_type(8)));
typedef __bf16 bf16x4 __attribute__((ext_vector_type(4)));
typedef float f32x4 __attribute__((ext_vector_type(4)));
typedef short short4v __attribute__((ext_vector_type(4)));

#if __has_builtin(__builtin_amdgcn_exp2f)
#define EXP2F __builtin_amdgcn_exp2f
#else
#define EXP2F exp2f
#endif

// ---------------- constants (problem shape is fixed) ----------------
#define BATCH 2
#define SEQ   2048
#define DIM   1024
#define NQH   16
#define NKVH  4
#define HD    64
#define ROWS  (BATCH*SEQ)      // 4096
#define QKVN  1536             // 1024 q + 256 k + 256 v
#define QSCALE 0.1803368801111f   // 0.125 * log2(e), folded into Q at projection

static __device__ __forceinline__ short4v as_s4(bf16x4 v) {
    union { bf16x4 b; short4v s; } u; u.b = v; return u.s;
}

// async global->LDS DMA, 16B per lane, LDS dest = wave-uniform base + lane*16
static __device__ __forceinline__ void gld16(const bf16_t* g, bf16_t* l) {
    __builtin_amdgcn_global_load_lds((const __attribute__((address_space(1))) void*)g,
                                     (__attribute__((address_space(3))) void*)l,
                                     16, 0, 0);
}

// ======================= prep: cast x -> bf16  +  all 4 weight transposes (ONE dispatch) =======================
// Blocks 0..639: weight transpose (64x64 f32 tile via LDS). Blocks 640..4735:
// cast 1024 floats each. Merging saves one serial launch gap and co-schedules
// the two phases across CUs (cast is BW-bound, transpose is LDS-bound).
__global__ __launch_bounds__(256) void prep_kernel(const float* __restrict__ x,
                                                   const float* __restrict__ wq,
                                                   const float* __restrict__ wk,
                                                   const float* __restrict__ wv,
                                                   const float* __restrict__ wo,
                                                   bf16_t* __restrict__ Xb,
                                                   bf16_t* __restrict__ WqkvT,
                                                   bf16_t* __restrict__ WoT) {
    int bid = blockIdx.x;
    int t = threadIdx.x;
    if (bid >= 640) {                      // ---- cast path ----
        size_t i = ((size_t)(bid - 640) * 256 + t) * 4;
        float4 v = *(const float4*)(x + i);
        bf16x4 r;
        r[0] = (bf16_t)v.x; r[1] = (bf16_t)v.y; r[2] = (bf16_t)v.z; r[3] = (bf16_t)v.w;
        *(bf16x4*)(Xb + i) = r;
        return;
    }
    // ---- transpose path ----
    const float* src; bf16_t* dst; int N, nt, kt2;
    if (bid < 256)      { src = wq; dst = WqkvT;                      N = 1024; int i = bid;       nt = i & 15; kt2 = i >> 4; }
    else if (bid < 320) { src = wk; dst = WqkvT + (size_t)1024*1024;  N = 256;  int i = bid - 256; nt = i & 3;  kt2 = i >> 2; }
    else if (bid < 384) { src = wv; dst = WqkvT + (size_t)1280*1024;  N = 256;  int i = bid - 320; nt = i & 3;  kt2 = i >> 2; }
    else                { src = wo; dst = WoT;                        N = 1024; int i = bid - 384; nt = i & 15; kt2 = i >> 4; }

    __shared__ float tile[64][65];
    {
        int r = t >> 2, cb = (t & 3) * 16;
        const float* s = src + (size_t)(kt2 * 64 + r) * N + nt * 64 + cb;
#pragma unroll
        for (int j = 0; j < 16; j += 4) {
            float4 v = *(const float4*)(s + j);
            tile[r][cb + j + 0] = v.x; tile[r][cb + j + 1] = v.y;
            tile[r][cb + j + 2] = v.z; tile[r][cb + j + 3] = v.w;
        }
    }
    __syncthreads();
    {
        int n = t >> 2, kb = (t & 3) * 16;
        union { bf16_t h[16]; uint4 u[2]; } pk;
#pragma unroll
        for (int j = 0; j < 16; ++j) pk.h[j] = (bf16_t)tile[kb + j][n];
        bf16_t* d = dst + (size_t)(nt * 64 + n) * 1024 + kt2 * 64 + kb;
        ((uint4*)d)[0] = pk.u[0];
        ((uint4*)d)[1] = pk.u[1];
    }
}

// ======================= GEMM1: x @ Wqkv^T, BM=64 BN=128 BK=64, fused RoPE (R4/R9 proven) =======================
__global__ __launch_bounds__(256, 3) void gemm_qkv_kernel(const bf16_t* __restrict__ A,
                                                          const bf16_t* __restrict__ Bt,
                                                          const float* __restrict__ fcos,
                                                          const float* __restrict__ fsin,
                                                          bf16_t* __restrict__ Qb,
                                                          bf16_t* __restrict__ Kb,
                                                          bf16_t* __restrict__ Vt) {
    const int K = 1024;
    __shared__ __align__(16) bf16_t As[64 * 64];
    __shared__ __align__(16) bf16_t Bs[128 * 64];
    int t = threadIdx.x;
    int w = t >> 6, L = t & 63, quad = L >> 4, l15 = L & 15;
    int wr = (w >> 1) * 32, wc = (w & 1) * 64;

    int xid = blockIdx.x;                  // 0..767
    int sw = (xid & 7) * 96 + (xid >> 3);  // bijective XCD swizzle (768 % 8 == 0)
    int bnb = sw % 12;
    int bm = (sw / 12) * 64, bn = bnb * 128;

    int srow = L >> 3;                     // 0..7
    int schunk = (L & 7) ^ srow;           // pre-swizzled global source chunk
    const bf16_t* Ag = A  + (size_t)(bm + w * 16 + srow) * K + schunk * 8;
    const bf16_t* Bg = Bt + (size_t)(bn + w * 32 + srow) * K + schunk * 8;
    bf16_t* Al = As + w * 1024;
    bf16_t* Bl = Bs + w * 2048;

    int rs0 = quad ^ (l15 & 7);            // read slot, kk=0
    int rs1 = (4 + quad) ^ (l15 & 7);      // read slot, kk=1

    f32x4 acc[2][4] = {};

    for (int k0 = 0; k0 < K; k0 += 64) {
        __syncthreads();
        gld16(Ag + k0,                 Al);
        gld16(Ag + (size_t)8 * K + k0, Al + 512);
#pragma unroll
        for (int c = 0; c < 4; ++c)
            gld16(Bg + (size_t)(c * 8) * K + k0, Bl + c * 512);
        __syncthreads();

#pragma unroll
        for (int kk = 0; kk < 2; ++kk) {
            int rsl = kk ? rs1 : rs0;
            bf16x8 a[2], b[4];
#pragma unroll
            for (int i = 0; i < 2; ++i)
                a[i] = ((const bf16x8*)As)[(wr + 16 * i + l15) * 8 + rsl];
#pragma unroll
            for (int j = 0; j < 4; ++j)
                b[j] = ((const bf16x8*)Bs)[(wc + 16 * j + l15) * 8 + rsl];
#pragma unroll
            for (int i = 0; i < 2; ++i)
#pragma unroll
                for (int j = 0; j < 4; ++j)
                    acc[i][j] = __builtin_amdgcn_mfma_f32_16x16x32_bf16(a[i], b[j], acc[i][j], 0, 0, 0);
        }
    }

    // ---- fused epilogue ----
    int region = (bnb >= 10) ? 2 : (bnb >= 8) ? 1 : 0;
#pragma unroll
    for (int i = 0; i < 2; ++i) {
        int row0 = bm + wr + 16 * i + quad * 4;
        int b = row0 >> 11, s0 = row0 & 2047;
#pragma unroll
        for (int j = 0; j < 4; ++j) {
            int col = bn + wc + 16 * j + l15;
            if (region == 2) {                      // V: write Vt[b][kv][d][s], 4 consecutive s
                int kvh = (col >> 6) - 20, d = col & 63;
                bf16x4 o;
#pragma unroll
                for (int r = 0; r < 4; ++r) o[r] = (bf16_t)acc[i][j][r];
                *(bf16x4*)(Vt + ((size_t)((b * NKVH + kvh) * HD + d)) * SEQ + s0) = o;
            } else {                                // Q or K: RoPE
                int d = col & 63, fi = d >> 1;
                int odd = col & 1;
#pragma unroll
                for (int r = 0; r < 4; ++r) {
                    int s = s0 + r;
                    float v = acc[i][j][r];
                    float p = __shfl_xor(v, 1);
                    float c = fcos[s * 32 + fi], sn = fsin[s * 32 + fi];
                    float o = odd ? (p * sn + v * c) : (v * c - p * sn);
                    if (region == 0) {
                        int h = col >> 6;
                        Qb[((size_t)((b * NQH + h) * SEQ + s)) * HD + d] = (bf16_t)(o * QSCALE);
                    } else {
                        int kvh = (col >> 6) - 16;
                        Kb[((size_t)((b * NKVH + kvh) * SEQ + s)) * HD + d] = (bf16_t)o;
                    }
                }
            }
        }
    }
}

// ======================= GEMM2: attn @ Wo^T, BM=64 BN=128 BK=64 (R4/R9 proven) =======================
__global__ __launch_bounds__(256, 2) void gemm_bt_kernel(const bf16_t* __restrict__ A,
                                                         const bf16_t* __restrict__ Bt,
                                                         float* __restrict__ C) {
    const int K = 1024, N = 1024;
    __shared__ __align__(16) bf16_t As[64 * 64];
    __shared__ __align__(16) bf16_t Bs[128 * 64];
    int t = threadIdx.x;
    int w = t >> 6, L = t & 63, quad = L >> 4, l15 = L & 15;
    int wr = (w >> 1) * 32, wc = (w & 1) * 64;

    int xid = blockIdx.x;                  // 0..511
    int sw = (xid & 7) * 64 + (xid >> 3);  // bijective XCD swizzle (512 % 8 == 0)
    int bm = (sw >> 3) * 64, bn = (sw & 7) * 128;

    int srow = L >> 3;
    int schunk = (L & 7) ^ srow;
    const bf16_t* Ag = A  + (size_t)(bm + w * 16 + srow) * K + schunk * 8;
    const bf16_t* Bg = Bt + (size_t)(bn + w * 32 + srow) * K + schunk * 8;
    bf16_t* Al = As + w * 1024;
    bf16_t* Bl = Bs + w * 2048;

    int rs0 = quad ^ (l15 & 7);
    int rs1 = (4 + quad) ^ (l15 & 7);

    f32x4 acc[2][4] = {};

    for (int k0 = 0; k0 < K; k0 += 64) {
        __syncthreads();
        gld16(Ag + k0,                 Al);
        gld16(Ag + (size_t)8 * K + k0, Al + 512);
#pragma unroll
        for (int c = 0; c < 4; ++c)
            gld16(Bg + (size_t)(c * 8) * K + k0, Bl + c * 512);
        __syncthreads();

#pragma unroll
        for (int kk = 0; kk < 2; ++kk) {
            int rsl = kk ? rs1 : rs0;
            bf16x8 a[2], b[4];
#pragma unroll
            for (int i = 0; i < 2; ++i)
                a[i] = ((const bf16x8*)As)[(wr + 16 * i + l15) * 8 + rsl];
#pragma unroll
            for (int j = 0; j < 4; ++j)
                b[j] = ((const bf16x8*)Bs)[(wc + 16 * j + l15) * 8 + rsl];
#pragma unroll
            for (int i = 0; i < 2; ++i)
#pragma unroll
                for (int j = 0; j < 4; ++j)
                    acc[i][j] = __builtin_amdgcn_mfma_f32_16x16x32_bf16(a[i], b[j], acc[i][j], 0, 0, 0);
        }
    }

#pragma unroll
    for (int i = 0; i < 2; ++i) {
        int row = bm + wr + 16 * i + quad * 4;
#pragma unroll
        for (int j = 0; j < 4; ++j) {
            int col = bn + wc + 16 * j + l15;
            float* cp = C + (size_t)row * N + col;
#pragma unroll
            for (int r = 0; r < 4; ++r)
                cp[(size_t)r * N] = acc[i][j][r];
        }
    }
}

// ======================= flash attention, causal, GQA 4:1 — KEY-SPLIT WAVES (R9, kept) =======================
__global__ __launch_bounds__(256, 2) void attn_kernel(const bf16_t* __restrict__ Qb,
                                                      const bf16_t* __restrict__ Kb,
                                                      const bf16_t* __restrict__ Vt,
                                                      bf16_t* __restrict__ Ob) {
    int id = blockIdx.x;                       // 0..511
    int sw = (id & 7) * 64 + (id >> 3);        // bijective XCD swizzle (512 % 8 == 0)
    int b  = sw >> 8;
    int kv = (sw >> 6) & 3;
    int h  = kv * 4 + ((sw >> 4) & 3);
    int p  = sw & 15;                          // q-tiles {p, 31-p}

    int t = threadIdx.x, w = t >> 6, lane = t & 63, quad = lane >> 4, l15 = lane & 15;

    // 69632 B aliased: staging {Ks[2] 2x8192 elems, Vs[2] 2x8192 elems} / reduction f32[4][64][68]
    __shared__ __align__(16) char smem[69632];
    __shared__ float rsw[4][64];
    bf16_t* KsBuf = (bf16_t*)smem;             // Ks[buf] at buf*8192 elems
    bf16_t* VsBuf = (bf16_t*)smem + 16384;     // Vs[buf] at buf*8192 elems
    float*  red   = (float*)smem;              // [w][q 64][d 68] idx = w*4352 + q*68 + d

    const bf16_t* Qbase = Qb + ((size_t)(b * NQH + h)) * SEQ * HD;
    const bf16_t* Kbase = Kb + ((size_t)(b * NKVH + kv)) * SEQ * HD;
    const bf16_t* Vbase = Vt + ((size_t)(b * NKVH + kv)) * HD * SEQ;

    // staging: K chunk o=t+256j: row=o>>3,c=o&7; V: row=o>>4,c=o&15; src chunk c^(row&7)
    const bf16_t* kS0 = Kbase + (size_t)(t >> 3) * HD + (size_t)(((t & 7) ^ ((t >> 3) & 7)) * 8);
    const bf16_t* vS0 = Vbase + (size_t)(t >> 4) * SEQ + (size_t)(((t & 15) ^ ((t >> 4) & 7)) * 8);
    int ldso = w * 512;

#pragma unroll 1
    for (int ph = 0; ph < 2; ++ph) {
        int qt = ph ? (31 - p) : p;
        int Q0 = qt * 64;
        int ktmax = qt >> 1;                   // inclusive, 128-key tiles

        bf16x8 aq[4][2];                       // ALL 64 q-rows in registers
#pragma unroll
        for (int j = 0; j < 4; ++j)
#pragma unroll
            for (int ks = 0; ks < 2; ++ks)
                aq[j][ks] = *(const bf16x8*)(Qbase + (size_t)(Q0 + 16 * j + l15) * HD + ks * 32 + quad * 8);

        f32x4 acc[4][4] = {};                  // partial O over this wave's keys
        float rs[4] = {};

        __syncthreads();                       // prev-phase reduction reads done
#pragma unroll
        for (int j4 = 0; j4 < 4; ++j4) {
            gld16(kS0 + (size_t)j4 * 32 * HD,  KsBuf + ldso + j4 * 2048);
            gld16(vS0 + (size_t)j4 * 16 * SEQ, VsBuf + ldso + j4 * 2048);
        }

        int cur = 0;
        for (int kt = 0; kt <= ktmax; ++kt) {
            __syncthreads();                   // drains own gld16; buf[cur] ready
            if (kt < ktmax) {
                const bf16_t* kp = kS0 + (size_t)(kt + 1) * 128 * HD;
                const bf16_t* vp = vS0 + (size_t)(kt + 1) * 128;
                bf16_t* kd = KsBuf + (cur ^ 1) * 8192 + ldso;
                bf16_t* vd = VsBuf + (cur ^ 1) * 8192 + ldso;
#pragma unroll
                for (int j4 = 0; j4 < 4; ++j4) {
                    gld16(kp + (size_t)j4 * 32 * HD,  kd + j4 * 2048);
                    gld16(vp + (size_t)j4 * 16 * SEQ, vd + j4 * 2048);
                }
            }
            const bf16_t* KsC = KsBuf + cur * 8192;
            const bf16_t* VsC = VsBuf + cur * 8192;

            // even-qt diagonal: waves 2,3 fully masked -> uniform skip
            if (!(kt == ktmax && !(qt & 1) && w >= 2)) {
                short4v bp[2][4];
                if (kt == ktmax) {             // diagonal tile: mask
#pragma unroll
                    for (int g2 = 0; g2 < 2; ++g2) {
                        int g = 2 * w + g2;
                        int keyl = 16 * g + l15;
                        bf16x8 ak0 = ((const bf16x8*)KsC)[keyl * 8 + (quad ^ (keyl & 7))];
                        bf16x8 ak1 = ((const bf16x8*)KsC)[keyl * 8 + ((4 + quad) ^ (keyl & 7))];
                        int kb = kt * 128 + 16 * g + quad * 4;
#pragma unroll
                        for (int j = 0; j < 4; ++j) {
                            f32x4 z = {0.f, 0.f, 0.f, 0.f};
                            z = __builtin_amdgcn_mfma_f32_16x16x32_bf16(ak0, aq[j][0], z, 0, 0, 0);
                            z = __builtin_amdgcn_mfma_f32_16x16x32_bf16(ak1, aq[j][1], z, 0, 0, 0);
                            int qrow = Q0 + 16 * j + l15;
                            bf16x4 pb;
#pragma unroll
                            for (int r = 0; r < 4; ++r) {
                                float pv = (kb + r <= qrow) ? EXP2F(z[r]) : 0.f;
                                rs[j] += pv; pb[r] = (bf16_t)pv;
                            }
                            bp[g2][j] = as_s4(pb);
                        }
                    }
                } else {                       // interior tile: no mask
#pragma unroll
                    for (int g2 = 0; g2 < 2; ++g2) {
                        int g = 2 * w + g2;
                        int keyl = 16 * g + l15;
                        bf16x8 ak0 = ((const bf16x8*)KsC)[keyl * 8 + (quad ^ (keyl & 7))];
                        bf16x8 ak1 = ((const bf16x8*)KsC)[keyl * 8 + ((4 + quad) ^ (keyl & 7))];
#pragma unroll
                        for (int j = 0; j < 4; ++j) {
                            f32x4 z = {0.f, 0.f, 0.f, 0.f};
                            z = __builtin_amdgcn_mfma_f32_16x16x32_bf16(ak0, aq[j][0], z, 0, 0, 0);
                            z = __builtin_amdgcn_mfma_f32_16x16x32_bf16(ak1, aq[j][1], z, 0, 0, 0);
                            bf16x4 pb;
#pragma unroll
                            for (int r = 0; r < 4; ++r) {
                                float pv = EXP2F(z[r]);
                                rs[j] += pv; pb[r] = (bf16_t)pv;
                            }
                            bp[g2][j] = as_s4(pb);
                        }
                    }
                }

                // ---- O^T partial += V^T(this wave's keys) · P^T ----
                __builtin_amdgcn_s_setprio(1);
#pragma unroll
                for (int dt = 0; dt < 4; ++dt) {
                    int d = 16 * dt + l15;
#pragma unroll
                    for (int g2 = 0; g2 < 2; ++g2) {
                        int g = 2 * w + g2;
                        int pos = (2 * g + (quad >> 1)) ^ (d & 7);
                        bf16x4 av = *(const bf16x4*)(VsC + d * 128 + pos * 8 + (quad & 1) * 4);
#pragma unroll
                        for (int j = 0; j < 4; ++j)
                            acc[dt][j] = __builtin_amdgcn_mfma_f32_16x16x16bf16_1k(as_s4(av), bp[g2][j], acc[dt][j], 0, 0, 0);
                    }
                }
                __builtin_amdgcn_s_setprio(0);
            }
            cur ^= 1;
        }

        // ---- cross-wave reduction ----
        __syncthreads();                       // all K/V LDS reads done; DMA drained
        {
            float* rw = red + w * 4352;
#pragma unroll
            for (int dt = 0; dt < 4; ++dt)
#pragma unroll
                for (int j = 0; j < 4; ++j)
                    *(f32x4*)(rw + (16 * j + l15) * 68 + 16 * dt + quad * 4) = acc[dt][j];
        }
#pragma unroll
        for (int j = 0; j < 4; ++j) {
            float v = rs[j];
            v += __shfl_xor(v, 16);
            v += __shfl_xor(v, 32);
            if (quad == 0) rsw[w][16 * j + l15] = v;
        }
        __syncthreads();                       // partials + rowsums visible

        // wave w writes d-range [16w,16w+16) for all 64 q (lane = q)
        {
            int qg = Q0 + lane;
            float rtot = rsw[0][lane] + rsw[1][lane] + rsw[2][lane] + rsw[3][lane];
            float rinv = 1.0f / rtot;
            union { bf16_t hh[16]; uint4 u[2]; } pk;
#pragma unroll
            for (int dq = 0; dq < 4; ++dq) {
                f32x4 s = *(const f32x4*)(red + lane * 68 + 16 * w + 4 * dq);
#pragma unroll
                for (int w2 = 1; w2 < 4; ++w2) {
                    f32x4 tp = *(const f32x4*)(red + w2 * 4352 + lane * 68 + 16 * w + 4 * dq);
                    s[0] += tp[0]; s[1] += tp[1]; s[2] += tp[2]; s[3] += tp[3];
                }
#pragma unroll
                for (int r = 0; r < 4; ++r) pk.hh[4 * dq + r] = (bf16_t)(s[r] * rinv);
            }
            bf16_t* ob = Ob + (size_t)(b * SEQ + qg) * DIM + h * HD + 16 * w;
            ((uint4*)ob)[0] = pk.u[0];
            ((uint4*)ob)[1] = pk.u[1];
        }
    }
}

// ======================= launcher =======================
extern "C" void kernel_launch(void* const* d_in, const int* in_sizes, int n_in,
                              void* d_out, int out_size, void* d_ws, size_t ws_size,
                              hipStream_t stream) {
    const float* x    = (const float*)d_in[0];
    const float* fcos = (const float*)d_in[2];
    const float* fsin = (const float*)d_in[3];
    const float* wq   = (const float*)d_in[5];
    const float* wk   = (const float*)d_in[6];
    const float* wv   = (const float*)d_in[7];
    const float* wo   = (const float*)d_in[8];
    float* out = (float*)d_out;

    char* ws = (char*)d_ws;
    bf16_t* Xb    = (bf16_t*)(ws + 0);            //  8 MB  [4096][1024]
    bf16_t* Attnb = Xb;                           // alias (Xb dead after gemm_qkv)
    bf16_t* WqkvT = (bf16_t*)(ws + 8388608);      //  3 MB  [1536][1024]
    bf16_t* WoT   = (bf16_t*)(ws + 11534336);     //  2 MB  [1024][1024]
    bf16_t* Qb    = (bf16_t*)(ws + 13631488);     //  8 MB  [B][16][S][64]
    bf16_t* Kb    = (bf16_t*)(ws + 22020096);     //  2 MB  [B][4][S][64]
    bf16_t* Vt    = (bf16_t*)(ws + 24117248);     //  2 MB  [B][4][64][S]
    // total 26,214,400 B

    prep_kernel<<<640 + ROWS * DIM / 1024, 256, 0, stream>>>(x, wq, wk, wv, wo, Xb, WqkvT, WoT);

    gemm_qkv_kernel<<<(QKVN / 128) * (ROWS / 64), 256, 0, stream>>>(Xb, WqkvT, fcos, fsin, Qb, Kb, Vt);

    attn_kernel<<<512, 256, 0, stream>>>(Qb, Kb, Vt, Attnb);

    gemm_bt_kernel<<<(DIM / 128) * (ROWS / 64), 256, 0, stream>>>(Attnb, WoT, out);
}